// Round 15
// baseline (458.251 us; speedup 1.0000x reference)
//
#include <hip/hip_runtime.h>
#include <math.h>

#define IN_DIM 512
#define DD 256

typedef _Float16 half8_t __attribute__((ext_vector_type(8)));
typedef _Float16 half4_t __attribute__((ext_vector_type(4)));
typedef __attribute__((ext_vector_type(4))) float f32x4_t;

// ---- prep: w2[i] = W[i,:] . a_w[D:2D]; one wave per row, coalesced ----
__global__ __launch_bounds__(256) void prep_w2(const float* __restrict__ W,
                                               const float* __restrict__ a_w,
                                               float* __restrict__ w2) {
  int row = (blockIdx.x * 256 + threadIdx.x) >> 6;  // 0..255
  int lane = threadIdx.x & 63;
  if (row >= DD) return;
  float4 wv = *reinterpret_cast<const float4*>(&W[(size_t)row * DD + lane * 4]);
  float4 av = *reinterpret_cast<const float4*>(&a_w[DD + lane * 4]);
  float s = wv.x * av.x + wv.y * av.y + wv.z * av.z + wv.w * av.w;
#pragma unroll
  for (int d = 32; d; d >>= 1) s += __shfl_xor(s, d, 64);
  if (lane == 0) w2[row] = s;
}

// ---- convert Wm_o to MFMA-fragment-ordered fp16 ----
// chunk kc16 (K=32 slab) = 8192 halves; frag nf at [nf*512 .. +512): lane*8 + (k&7)
__global__ void bconv_kernel(const float* __restrict__ Wm, _Float16* __restrict__ Bh) {
  int i = blockIdx.x * 256 + threadIdx.x;  // 0..131071
  int k = i >> 8, col = i & 255;
  int kc16 = k >> 5, kr = k & 31;
  int lane = ((kr >> 3) << 4) | (col & 15);
  int nf = col >> 4;
  int off = (((((kc16 << 4) + nf) << 6) + lane) << 3) + (kr & 7);
  Bh[off] = (_Float16)Wm[i];
}

__device__ __forceinline__ half8_t cvt8(const float4& a, const float4& b) {
  half8_t h;
  h[0] = (_Float16)a.x; h[1] = (_Float16)a.y; h[2] = (_Float16)a.z; h[3] = (_Float16)a.w;
  h[4] = (_Float16)b.x; h[5] = (_Float16)b.y; h[6] = (_Float16)b.z; h[7] = (_Float16)b.w;
  return h;
}

// ---- MFMA GEMM, barrier-free: A direct-from-global (2-deep reg prefetch),
// B fragments read DIRECTLY from global (256KB, L2-hot in every XCD; lanes
// at l*16B -> coalesced 1KB/load). No LDS, no barriers, no fences -- the
// scheduler and 12 waves/CU of TLP hide all latency. In-register epilogue. ----
__global__ __launch_bounds__(256, 3) void map_gemm_mfma(
    const float* __restrict__ X, const _Float16* __restrict__ Bh,
    const float* __restrict__ bm, const float* __restrict__ w2,
    float* __restrict__ Yn, _Float16* __restrict__ Y16,
    float* __restrict__ wnorm, int M) {
  const int t = threadIdx.x;
  const int wv = t >> 6;
  const int l = t & 63;
  const int c = l & 15;
  const int g = l >> 4;
  const int row0 = blockIdx.x * 64 + wv * 16;  // wave's 16-row strip

  int arow = row0 + c;
  if (arow >= M) arow = M - 1;  // clamp; tail rows computed, never stored
  const float* xrow = X + (size_t)arow * IN_DIM;

  f32x4_t acc[16];
#pragma unroll
  for (int n = 0; n < 16; ++n) acc[n] = (f32x4_t){0.f, 0.f, 0.f, 0.f};

  const half8_t* bfr = reinterpret_cast<const half8_t*>(Bh);  // frag n of chunk kc at (kc*16+n)*64 + l

  // 2-deep A register prefetch (16 VGPR)
  float4 sA0[2], sA1[2];
  sA0[0] = *reinterpret_cast<const float4*>(xrow + g * 8);
  sA0[1] = *reinterpret_cast<const float4*>(xrow + g * 8 + 4);
  sA1[0] = *reinterpret_cast<const float4*>(xrow + 32 + g * 8);
  sA1[1] = *reinterpret_cast<const float4*>(xrow + 32 + g * 8 + 4);

#pragma unroll
  for (int kc = 0; kc < 16; ++kc) {
    // A fragment for this chunk (loaded 2 iterations ago) -- read BEFORE
    // the kc+2 prefetch overwrites its register set
    half8_t ah = ((kc & 1) == 0) ? cvt8(sA0[0], sA0[1]) : cvt8(sA1[0], sA1[1]);
    if (kc < 14) {
      const float* xp = xrow + (kc + 2) * 32 + g * 8;
      if ((kc & 1) == 0) {
        sA0[0] = *reinterpret_cast<const float4*>(xp);
        sA0[1] = *reinterpret_cast<const float4*>(xp + 4);
      } else {
        sA1[0] = *reinterpret_cast<const float4*>(xp);
        sA1[1] = *reinterpret_cast<const float4*>(xp + 4);
      }
    }
    const half8_t* bp = bfr + (kc << 4) * 64 + l;
#pragma unroll
    for (int n = 0; n < 16; ++n) {
      half8_t bh = bp[n << 6];  // coalesced 1KB L2-hit load
      acc[n] = __builtin_amdgcn_mfma_f32_16x16x32_f16(ah, bh, acc[n], 0, 0, 0);
    }
  }

  // ---- in-register epilogue: bias+relu, row-dot + row-norm (width-16
  // butterfly over c-lanes), wnorm = exp(dot)*||h||, normalized stores ----
  float ssq[4] = {0.f, 0.f, 0.f, 0.f}, dtq[4] = {0.f, 0.f, 0.f, 0.f};
#pragma unroll
  for (int n = 0; n < 16; ++n) {
    float bvn = bm[n * 16 + c];
    float wvn = w2[n * 16 + c];
#pragma unroll
    for (int q = 0; q < 4; ++q) {
      float v = acc[n][q] + bvn;
      v = v > 0.f ? v : 0.f;
      acc[n][q] = v;
      ssq[q] = fmaf(v, v, ssq[q]);
      dtq[q] = fmaf(v, wvn, dtq[q]);
    }
  }
#pragma unroll
  for (int q = 0; q < 4; ++q) {
#pragma unroll
    for (int d = 1; d < 16; d <<= 1) {
      ssq[q] += __shfl_xor(ssq[q], d, 16);
      dtq[q] += __shfl_xor(dtq[q], d, 16);
    }
  }
  float inv[4];
#pragma unroll
  for (int q = 0; q < 4; ++q) {
    float nr = sqrtf(ssq[q]);
    inv[q] = 1.f / fmaxf(nr, 1e-12f);
    int r = row0 + g * 4 + q;
    if (c == 0 && r < M) wnorm[r] = expf(dtq[q]) * nr;
  }
#pragma unroll
  for (int q = 0; q < 4; ++q) {
    int r = row0 + g * 4 + q;
    if (r < M) {
#pragma unroll
      for (int n = 0; n < 16; ++n) {
        float v = acc[n][q] * inv[q];
        Yn[(size_t)r * DD + n * 16 + c] = v;
        Y16[(size_t)r * DD + n * 16 + c] = (_Float16)v;
      }
    }
  }
}

// ---- CSR build ----
__global__ void hist_kernel(const int* __restrict__ src, int* __restrict__ deg, int E) {
  int i = blockIdx.x * blockDim.x + threadIdx.x;
  if (i < E) atomicAdd(&deg[src[i]], 1);
}

// hierarchical exclusive scan: 256 blocks x 256 thr x 2 items
__global__ __launch_bounds__(256) void scan_part(const int* __restrict__ deg,
                                                 int* __restrict__ bsum, int NP) {
  __shared__ int s[256];
  int t = threadIdx.x, b = blockIdx.x;
  int i0 = (b * 256 + t) * 2;
  int v0 = (i0 < NP) ? deg[i0] : 0;
  int v1 = (i0 + 1 < NP) ? deg[i0 + 1] : 0;
  s[t] = v0 + v1;
  __syncthreads();
  for (int off = 128; off; off >>= 1) {
    if (t < off) s[t] += s[t + off];
    __syncthreads();
  }
  if (t == 0) bsum[b] = s[0];
}

__global__ __launch_bounds__(256) void scan_top(int* __restrict__ bsum,
                                                int* __restrict__ rowptr_last) {
  __shared__ int s[256];
  int t = threadIdx.x;
  int v = bsum[t];
  s[t] = v;
  __syncthreads();
  for (int off = 1; off < 256; off <<= 1) {
    int u = (t >= off) ? s[t - off] : 0;
    __syncthreads();
    s[t] += u;
    __syncthreads();
  }
  bsum[t] = s[t] - v;  // exclusive
  if (t == 255) *rowptr_last = s[255];
}

__global__ __launch_bounds__(256) void scan_fin(const int* __restrict__ deg,
                                                const int* __restrict__ bsum,
                                                int* __restrict__ rowptr,
                                                int* __restrict__ cursor, int NP) {
  __shared__ int s[256];
  int t = threadIdx.x, b = blockIdx.x;
  int i0 = (b * 256 + t) * 2;
  int v0 = (i0 < NP) ? deg[i0] : 0;
  int v1 = (i0 + 1 < NP) ? deg[i0 + 1] : 0;
  int local = v0 + v1;
  s[t] = local;
  __syncthreads();
  for (int off = 1; off < 256; off <<= 1) {
    int u = (t >= off) ? s[t - off] : 0;
    __syncthreads();
    s[t] += u;
    __syncthreads();
  }
  int base = bsum[b] + s[t] - local;
  if (i0 < NP) { rowptr[i0] = base; cursor[i0] = base; }
  if (i0 + 1 < NP) { rowptr[i0 + 1] = base + v0; cursor[i0 + 1] = base + v0; }
}

__global__ void fill_kernel(const int* __restrict__ src, const int* __restrict__ dst,
                            int* __restrict__ cursor, int* __restrict__ ebuf, int E) {
  int i = blockIdx.x * blockDim.x + threadIdx.x;
  if (i < E) {
    int pos = atomicAdd(&cursor[src[i]], 1);
    ebuf[pos] = dst[i];
  }
}

// ---- per-segment: out = l2norm(sum wnorm[d] * hon16[d])
// (softmax denom is a positive segment constant -> vanishes under l2norm) ----
__global__ void agg_kernel(const int* __restrict__ rowptr, const int* __restrict__ ebuf,
                           const float* __restrict__ wnorm, const _Float16* __restrict__ hon16,
                           float* __restrict__ agg, int NP) {
  int p = (int)(((long)blockIdx.x * blockDim.x + threadIdx.x) >> 6);
  int lane = threadIdx.x & 63;
  if (p >= NP) return;
  int beg = rowptr[p], end = rowptr[p + 1];
  float4 acc = {0.f, 0.f, 0.f, 0.f};
  if (beg < end) {
    // 2-deep pipelined weighted row gather (fp16 rows: 8B/lane)
    int d0 = ebuf[beg];
    float w0 = wnorm[d0];
    half4_t v0 = *reinterpret_cast<const half4_t*>(&hon16[(size_t)d0 * DD + lane * 4]);
    float w1 = 0.f;
    half4_t v1 = {0, 0, 0, 0};
    if (beg + 1 < end) {
      int d1 = ebuf[beg + 1];
      w1 = wnorm[d1];
      v1 = *reinterpret_cast<const half4_t*>(&hon16[(size_t)d1 * DD + lane * 4]);
    }
    for (int j = beg; j < end; ++j) {
      float wn_ = 0.f;
      half4_t vn = {0, 0, 0, 0};
      if (j + 2 < end) {
        int dn = ebuf[j + 2];
        wn_ = wnorm[dn];
        vn = *reinterpret_cast<const half4_t*>(&hon16[(size_t)dn * DD + lane * 4]);
      }
      acc.x = fmaf(w0, (float)v0[0], acc.x);
      acc.y = fmaf(w0, (float)v0[1], acc.y);
      acc.z = fmaf(w0, (float)v0[2], acc.z);
      acc.w = fmaf(w0, (float)v0[3], acc.w);
      w0 = w1; v0 = v1; w1 = wn_; v1 = vn;
    }
  }
  float ss = acc.x * acc.x + acc.y * acc.y + acc.z * acc.z + acc.w * acc.w;
#pragma unroll
  for (int d = 32; d > 0; d >>= 1) ss += __shfl_xor(ss, d, 64);
  float inv = 1.0f / fmaxf(sqrtf(ss), 1e-12f);
  float4 o = {acc.x * inv, acc.y * inv, acc.z * inv, acc.w * inv};
  *reinterpret_cast<float4*>(&agg[(size_t)p * DD + lane * 4]) = o;
}

extern "C" void kernel_launch(void* const* d_in, const int* in_sizes, int n_in,
                              void* d_out, int out_size, void* d_ws, size_t ws_size,
                              hipStream_t stream) {
  const float* feat_other = (const float*)d_in[1];
  const int* src = (const int*)d_in[2];
  const int* dst = (const int*)d_in[3];
  const float* Wm_o = (const float*)d_in[6];
  const float* bm_o = (const float*)d_in[7];
  const float* W = (const float*)d_in[8];
  const float* a_w = (const float*)d_in[10];

  const int NP = in_sizes[0] / IN_DIM;
  const int NO = in_sizes[1] / IN_DIM;
  const int E = in_sizes[2];

  float* out = (float*)d_out;
  float* agg_out = out;                      // [NP, DD] (normalized agg)
  float* ho_out = out + (size_t)NP * DD;     // [NO, DD] (normalized ho)

  // workspace layout (floats)
  float* ws = (float*)d_ws;
  float* wnorm = ws;                          // NO
  float* w2 = wnorm + NO;                     // 256
  int* deg = (int*)(w2 + 256);                // NP (memset 0)
  int* rowptr = deg + NP;                     // NP+1
  int* cursor = rowptr + NP + 1;              // NP
  int* bsum = cursor + NP;                    // 256
  int* ebuf = bsum + 256;                     // E
  size_t foff = (size_t)NO + 256 + NP + (NP + 1) + NP + 256 + E;
  foff = (foff + 3) & ~(size_t)3;             // 16B align
  _Float16* Bh = (_Float16*)(ws + foff);      // 131072 halves
  _Float16* Y16 = Bh + (size_t)IN_DIM * DD;   // NO * DD halves

  hipMemsetAsync(deg, 0, (size_t)NP * sizeof(int), stream);

  prep_w2<<<64, 256, 0, stream>>>(W, a_w, w2);
  bconv_kernel<<<(IN_DIM * DD) / 256, 256, 0, stream>>>(Wm_o, Bh);

  map_gemm_mfma<<<(NO + 63) / 64, 256, 0, stream>>>(
      feat_other, Bh, bm_o, w2, ho_out, Y16, wnorm, NO);

  hist_kernel<<<(E + 255) / 256, 256, 0, stream>>>(src, deg, E);
  scan_part<<<256, 256, 0, stream>>>(deg, bsum, NP);
  scan_top<<<1, 256, 0, stream>>>(bsum, rowptr + NP);
  scan_fin<<<256, 256, 0, stream>>>(deg, bsum, rowptr, cursor, NP);
  fill_kernel<<<(E + 255) / 256, 256, 0, stream>>>(src, dst, cursor, ebuf, E);

  agg_kernel<<<(NP * 64 + 255) / 256, 256, 0, stream>>>(
      rowptr, ebuf, wnorm, Y16, agg_out, NP);
}

// Round 16
// 356.777 us; speedup vs baseline: 1.2844x; 1.2844x over previous
//
#include <hip/hip_runtime.h>
#include <math.h>

#define IN_DIM 512
#define DD 256

typedef _Float16 half8_t __attribute__((ext_vector_type(8)));
typedef _Float16 half4_t __attribute__((ext_vector_type(4)));
typedef __attribute__((ext_vector_type(4))) float f32x4_t;

// ---- prep: w2[i] = W[i,:] . a_w[D:2D]; one wave per row, coalesced ----
__global__ __launch_bounds__(256) void prep_w2(const float* __restrict__ W,
                                               const float* __restrict__ a_w,
                                               float* __restrict__ w2) {
  int row = (blockIdx.x * 256 + threadIdx.x) >> 6;  // 0..255
  int lane = threadIdx.x & 63;
  if (row >= DD) return;
  float4 wv = *reinterpret_cast<const float4*>(&W[(size_t)row * DD + lane * 4]);
  float4 av = *reinterpret_cast<const float4*>(&a_w[DD + lane * 4]);
  float s = wv.x * av.x + wv.y * av.y + wv.z * av.z + wv.w * av.w;
#pragma unroll
  for (int d = 32; d; d >>= 1) s += __shfl_xor(s, d, 64);
  if (lane == 0) w2[row] = s;
}

// ---- convert Wm_o to MFMA-fragment-ordered fp16 ----
// chunk kc16 (K=32 slab) = 8192 halves; frag nf at [nf*512 .. +512): lane*8 + (k&7)
__global__ void bconv_kernel(const float* __restrict__ Wm, _Float16* __restrict__ Bh) {
  int i = blockIdx.x * 256 + threadIdx.x;  // 0..131071
  int k = i >> 8, col = i & 255;
  int kc16 = k >> 5, kr = k & 31;
  int lane = ((kr >> 3) << 4) | (col & 15);
  int nf = col >> 4;
  int off = (((((kc16 << 4) + nf) << 6) + lane) << 3) + (kr & 7);
  Bh[off] = (_Float16)Wm[i];
}

__device__ __forceinline__ half8_t cvt8(const float4& a, const float4& b) {
  half8_t h;
  h[0] = (_Float16)a.x; h[1] = (_Float16)a.y; h[2] = (_Float16)a.z; h[3] = (_Float16)a.w;
  h[4] = (_Float16)b.x; h[5] = (_Float16)b.y; h[6] = (_Float16)b.z; h[7] = (_Float16)b.w;
  return h;
}

__device__ __forceinline__ void gload16(const void* g, void* l) {
  __builtin_amdgcn_global_load_lds(
      (const __attribute__((address_space(1))) void*)g,
      (__attribute__((address_space(3))) void*)l, 16, 0, 0);
}

// ---- MFMA GEMM: 32 rows PER WAVE (128-row blocks) -> 2x arithmetic
// intensity per B-read vs the 16-row structure (B volume per K-step is the
// invariant cost; 32 MFMAs now amortize it). R14's verified pipeline:
// A direct-from-global 2-deep reg prefetch, B via global_load_lds into
// triple-buffered LDS, raw s_barrier + counted vmcnt(8), full fences. ----
__global__ __launch_bounds__(256, 2) void map_gemm_mfma(
    const float* __restrict__ X, const _Float16* __restrict__ Bh,
    const float* __restrict__ bm, const float* __restrict__ w2,
    float* __restrict__ Yn, _Float16* __restrict__ Y16,
    float* __restrict__ wnorm, int M) {
  __shared__ _Float16 Bs[3][8192];  // 3 x 16KB
  const int t = threadIdx.x;
  const int wv = t >> 6;
  const int l = t & 63;
  const int c = l & 15;
  const int g = l >> 4;
  const int row0 = blockIdx.x * 128 + wv * 32;  // wave's 32-row strip

  int arow0 = row0 + c;       if (arow0 >= M) arow0 = M - 1;
  int arow1 = row0 + 16 + c;  if (arow1 >= M) arow1 = M - 1;
  const float* xrow0 = X + (size_t)arow0 * IN_DIM;
  const float* xrow1 = X + (size_t)arow1 * IN_DIM;

  f32x4_t acc[2][16];
#pragma unroll
  for (int rf = 0; rf < 2; ++rf)
#pragma unroll
    for (int n = 0; n < 16; ++n) acc[rf][n] = (f32x4_t){0.f, 0.f, 0.f, 0.f};

  const char* bbytes = reinterpret_cast<const char*>(Bh);
  const int lane16 = l * 16;

  // ---- prologue: batch0 = {B chunk0 (4 gload), A chunk0 (4 float4)};
  //      fence; batch1 = {B1, A1}.  8 vm-ops per batch. ----
  float4 a0[2][2], a1[2][2];  // [row-frag][part], chunk-even / chunk-odd sets
#pragma unroll
  for (int j = 0; j < 4; ++j)
    gload16(bbytes + ((wv << 2) + j) * 1024 + lane16,
            (char*)&Bs[0][0] + ((wv << 2) + j) * 1024);
  a0[0][0] = *reinterpret_cast<const float4*>(xrow0 + g * 8);
  a0[0][1] = *reinterpret_cast<const float4*>(xrow0 + g * 8 + 4);
  a0[1][0] = *reinterpret_cast<const float4*>(xrow1 + g * 8);
  a0[1][1] = *reinterpret_cast<const float4*>(xrow1 + g * 8 + 4);
  asm volatile("" ::: "memory");  // pin batch0 before batch1 in vmcnt queue
#pragma unroll
  for (int j = 0; j < 4; ++j)
    gload16(bbytes + 16384 + ((wv << 2) + j) * 1024 + lane16,
            (char*)&Bs[1][0] + ((wv << 2) + j) * 1024);
  a1[0][0] = *reinterpret_cast<const float4*>(xrow0 + 32 + g * 8);
  a1[0][1] = *reinterpret_cast<const float4*>(xrow0 + 32 + g * 8 + 4);
  a1[1][0] = *reinterpret_cast<const float4*>(xrow1 + 32 + g * 8);
  a1[1][1] = *reinterpret_cast<const float4*>(xrow1 + 32 + g * 8 + 4);

#pragma unroll
  for (int kc = 0; kc < 16; ++kc) {
    // own-wave chunk-kc loads retired; counted: 8 newer (batch kc+1)
    if (kc < 15) {
      asm volatile("s_waitcnt vmcnt(8)" ::: "memory");
    } else {
      asm volatile("s_waitcnt vmcnt(0)" ::: "memory");
    }
    __builtin_amdgcn_s_barrier();  // all waves' chunk-kc portions in LDS
    asm volatile("" ::: "memory");           // IR fence: no mem op crosses barrier
    __builtin_amdgcn_sched_barrier(0);       // MIR fence: scheduler can't hoist

    // A fragments for this chunk (loaded 2 iterations ago) -- read BEFORE
    // their register set is overwritten by the kc+2 prefetch below
    half8_t ah0, ah1;
    if ((kc & 1) == 0) {
      ah0 = cvt8(a0[0][0], a0[0][1]);
      ah1 = cvt8(a0[1][0], a0[1][1]);
    } else {
      ah0 = cvt8(a1[0][0], a1[0][1]);
      ah1 = cvt8(a1[1][0], a1[1][1]);
    }

    // issue chunk kc+2: B via gload_lds into buf[(kc+2)%3], A into retired set
    if (kc < 14) {
      const char* gb = bbytes + (kc + 2) * 16384;
      char* lb = (char*)&Bs[(kc + 2) % 3][0];
#pragma unroll
      for (int j = 0; j < 4; ++j)
        gload16(gb + ((wv << 2) + j) * 1024 + lane16, lb + ((wv << 2) + j) * 1024);
      const float* xp0 = xrow0 + (kc + 2) * 32 + g * 8;
      const float* xp1 = xrow1 + (kc + 2) * 32 + g * 8;
      if ((kc & 1) == 0) {
        a0[0][0] = *reinterpret_cast<const float4*>(xp0);
        a0[0][1] = *reinterpret_cast<const float4*>(xp0 + 4);
        a0[1][0] = *reinterpret_cast<const float4*>(xp1);
        a0[1][1] = *reinterpret_cast<const float4*>(xp1 + 4);
      } else {
        a1[0][0] = *reinterpret_cast<const float4*>(xp0);
        a1[0][1] = *reinterpret_cast<const float4*>(xp0 + 4);
        a1[1][0] = *reinterpret_cast<const float4*>(xp1);
        a1[1][1] = *reinterpret_cast<const float4*>(xp1 + 4);
      }
    }

    const _Float16* bp = &Bs[kc % 3][0];
    __builtin_amdgcn_s_setprio(1);
#pragma unroll
    for (int n = 0; n < 16; ++n) {
      half8_t bh = *reinterpret_cast<const half8_t*>(&bp[n * 512 + l * 8]);
      acc[0][n] = __builtin_amdgcn_mfma_f32_16x16x32_f16(ah0, bh, acc[0][n], 0, 0, 0);
      acc[1][n] = __builtin_amdgcn_mfma_f32_16x16x32_f16(ah1, bh, acc[1][n], 0, 0, 0);
    }
    __builtin_amdgcn_s_setprio(0);
  }

  // ---- in-register epilogue per row-frag: bias+relu, row-dot + row-norm
  // (width-16 butterfly over c-lanes), wnorm = exp(dot)*||h||, stores ----
#pragma unroll
  for (int rf = 0; rf < 2; ++rf) {
    float ssq[4] = {0.f, 0.f, 0.f, 0.f}, dtq[4] = {0.f, 0.f, 0.f, 0.f};
#pragma unroll
    for (int n = 0; n < 16; ++n) {
      float bvn = bm[n * 16 + c];
      float wvn = w2[n * 16 + c];
#pragma unroll
      for (int q = 0; q < 4; ++q) {
        float v = acc[rf][n][q] + bvn;
        v = v > 0.f ? v : 0.f;
        acc[rf][n][q] = v;
        ssq[q] = fmaf(v, v, ssq[q]);
        dtq[q] = fmaf(v, wvn, dtq[q]);
      }
    }
#pragma unroll
    for (int q = 0; q < 4; ++q) {
#pragma unroll
      for (int d = 1; d < 16; d <<= 1) {
        ssq[q] += __shfl_xor(ssq[q], d, 16);
        dtq[q] += __shfl_xor(dtq[q], d, 16);
      }
    }
    float inv[4];
#pragma unroll
    for (int q = 0; q < 4; ++q) {
      float nr = sqrtf(ssq[q]);
      inv[q] = 1.f / fmaxf(nr, 1e-12f);
      int r = row0 + rf * 16 + g * 4 + q;
      if (c == 0 && r < M) wnorm[r] = expf(dtq[q]) * nr;
    }
#pragma unroll
    for (int q = 0; q < 4; ++q) {
      int r = row0 + rf * 16 + g * 4 + q;
      if (r < M) {
#pragma unroll
        for (int n = 0; n < 16; ++n) {
          float v = acc[rf][n][q] * inv[q];
          Yn[(size_t)r * DD + n * 16 + c] = v;
          Y16[(size_t)r * DD + n * 16 + c] = (_Float16)v;
        }
      }
    }
  }
}

// ---- CSR build ----
__global__ void hist_kernel(const int* __restrict__ src, int* __restrict__ deg, int E) {
  int i = blockIdx.x * blockDim.x + threadIdx.x;
  if (i < E) atomicAdd(&deg[src[i]], 1);
}

// hierarchical exclusive scan: 256 blocks x 256 thr x 2 items
__global__ __launch_bounds__(256) void scan_part(const int* __restrict__ deg,
                                                 int* __restrict__ bsum, int NP) {
  __shared__ int s[256];
  int t = threadIdx.x, b = blockIdx.x;
  int i0 = (b * 256 + t) * 2;
  int v0 = (i0 < NP) ? deg[i0] : 0;
  int v1 = (i0 + 1 < NP) ? deg[i0 + 1] : 0;
  s[t] = v0 + v1;
  __syncthreads();
  for (int off = 128; off; off >>= 1) {
    if (t < off) s[t] += s[t + off];
    __syncthreads();
  }
  if (t == 0) bsum[b] = s[0];
}

__global__ __launch_bounds__(256) void scan_top(int* __restrict__ bsum,
                                                int* __restrict__ rowptr_last) {
  __shared__ int s[256];
  int t = threadIdx.x;
  int v = bsum[t];
  s[t] = v;
  __syncthreads();
  for (int off = 1; off < 256; off <<= 1) {
    int u = (t >= off) ? s[t - off] : 0;
    __syncthreads();
    s[t] += u;
    __syncthreads();
  }
  bsum[t] = s[t] - v;  // exclusive
  if (t == 255) *rowptr_last = s[255];
}

__global__ __launch_bounds__(256) void scan_fin(const int* __restrict__ deg,
                                                const int* __restrict__ bsum,
                                                int* __restrict__ rowptr,
                                                int* __restrict__ cursor, int NP) {
  __shared__ int s[256];
  int t = threadIdx.x, b = blockIdx.x;
  int i0 = (b * 256 + t) * 2;
  int v0 = (i0 < NP) ? deg[i0] : 0;
  int v1 = (i0 + 1 < NP) ? deg[i0 + 1] : 0;
  int local = v0 + v1;
  s[t] = local;
  __syncthreads();
  for (int off = 1; off < 256; off <<= 1) {
    int u = (t >= off) ? s[t - off] : 0;
    __syncthreads();
    s[t] += u;
    __syncthreads();
  }
  int base = bsum[b] + s[t] - local;
  if (i0 < NP) { rowptr[i0] = base; cursor[i0] = base; }
  if (i0 + 1 < NP) { rowptr[i0 + 1] = base + v0; cursor[i0 + 1] = base + v0; }
}

__global__ void fill_kernel(const int* __restrict__ src, const int* __restrict__ dst,
                            int* __restrict__ cursor, int* __restrict__ ebuf, int E) {
  int i = blockIdx.x * blockDim.x + threadIdx.x;
  if (i < E) {
    int pos = atomicAdd(&cursor[src[i]], 1);
    ebuf[pos] = dst[i];
  }
}

// ---- per-segment: out = l2norm(sum wnorm[d] * hon16[d])
// (softmax denom is a positive segment constant -> vanishes under l2norm) ----
__global__ void agg_kernel(const int* __restrict__ rowptr, const int* __restrict__ ebuf,
                           const float* __restrict__ wnorm, const _Float16* __restrict__ hon16,
                           float* __restrict__ agg, int NP) {
  int p = (int)(((long)blockIdx.x * blockDim.x + threadIdx.x) >> 6);
  int lane = threadIdx.x & 63;
  if (p >= NP) return;
  int beg = rowptr[p], end = rowptr[p + 1];
  float4 acc = {0.f, 0.f, 0.f, 0.f};
  if (beg < end) {
    // 2-deep pipelined weighted row gather (fp16 rows: 8B/lane)
    int d0 = ebuf[beg];
    float w0 = wnorm[d0];
    half4_t v0 = *reinterpret_cast<const half4_t*>(&hon16[(size_t)d0 * DD + lane * 4]);
    float w1 = 0.f;
    half4_t v1 = {0, 0, 0, 0};
    if (beg + 1 < end) {
      int d1 = ebuf[beg + 1];
      w1 = wnorm[d1];
      v1 = *reinterpret_cast<const half4_t*>(&hon16[(size_t)d1 * DD + lane * 4]);
    }
    for (int j = beg; j < end; ++j) {
      float wn_ = 0.f;
      half4_t vn = {0, 0, 0, 0};
      if (j + 2 < end) {
        int dn = ebuf[j + 2];
        wn_ = wnorm[dn];
        vn = *reinterpret_cast<const half4_t*>(&hon16[(size_t)dn * DD + lane * 4]);
      }
      acc.x = fmaf(w0, (float)v0[0], acc.x);
      acc.y = fmaf(w0, (float)v0[1], acc.y);
      acc.z = fmaf(w0, (float)v0[2], acc.z);
      acc.w = fmaf(w0, (float)v0[3], acc.w);
      w0 = w1; v0 = v1; w1 = wn_; v1 = vn;
    }
  }
  float ss = acc.x * acc.x + acc.y * acc.y + acc.z * acc.z + acc.w * acc.w;
#pragma unroll
  for (int d = 32; d > 0; d >>= 1) ss += __shfl_xor(ss, d, 64);
  float inv = 1.0f / fmaxf(sqrtf(ss), 1e-12f);
  float4 o = {acc.x * inv, acc.y * inv, acc.z * inv, acc.w * inv};
  *reinterpret_cast<float4*>(&agg[(size_t)p * DD + lane * 4]) = o;
}

extern "C" void kernel_launch(void* const* d_in, const int* in_sizes, int n_in,
                              void* d_out, int out_size, void* d_ws, size_t ws_size,
                              hipStream_t stream) {
  const float* feat_other = (const float*)d_in[1];
  const int* src = (const int*)d_in[2];
  const int* dst = (const int*)d_in[3];
  const float* Wm_o = (const float*)d_in[6];
  const float* bm_o = (const float*)d_in[7];
  const float* W = (const float*)d_in[8];
  const float* a_w = (const float*)d_in[10];

  const int NP = in_sizes[0] / IN_DIM;
  const int NO = in_sizes[1] / IN_DIM;
  const int E = in_sizes[2];

  float* out = (float*)d_out;
  float* agg_out = out;                      // [NP, DD] (normalized agg)
  float* ho_out = out + (size_t)NP * DD;     // [NO, DD] (normalized ho)

  // workspace layout (floats)
  float* ws = (float*)d_ws;
  float* wnorm = ws;                          // NO
  float* w2 = wnorm + NO;                     // 256
  int* deg = (int*)(w2 + 256);                // NP (memset 0)
  int* rowptr = deg + NP;                     // NP+1
  int* cursor = rowptr + NP + 1;              // NP
  int* bsum = cursor + NP;                    // 256
  int* ebuf = bsum + 256;                     // E
  size_t foff = (size_t)NO + 256 + NP + (NP + 1) + NP + 256 + E;
  foff = (foff + 3) & ~(size_t)3;             // 16B align
  _Float16* Bh = (_Float16*)(ws + foff);      // 131072 halves
  _Float16* Y16 = Bh + (size_t)IN_DIM * DD;   // NO * DD halves

  hipMemsetAsync(deg, 0, (size_t)NP * sizeof(int), stream);

  prep_w2<<<64, 256, 0, stream>>>(W, a_w, w2);
  bconv_kernel<<<(IN_DIM * DD) / 256, 256, 0, stream>>>(Wm_o, Bh);

  map_gemm_mfma<<<(NO + 127) / 128, 256, 0, stream>>>(
      feat_other, Bh, bm_o, w2, ho_out, Y16, wnorm, NO);

  hist_kernel<<<(E + 255) / 256, 256, 0, stream>>>(src, deg, E);
  scan_part<<<256, 256, 0, stream>>>(deg, bsum, NP);
  scan_top<<<1, 256, 0, stream>>>(bsum, rowptr + NP);
  scan_fin<<<256, 256, 0, stream>>>(deg, bsum, rowptr, cursor, NP);
  fill_kernel<<<(E + 255) / 256, 256, 0, stream>>>(src, dst, cursor, ebuf, E);

  agg_kernel<<<(NP * 64 + 255) / 256, 256, 0, stream>>>(
      rowptr, ebuf, wnorm, Y16, agg_out, NP);
}

// Round 18
// 332.115 us; speedup vs baseline: 1.3798x; 1.0743x over previous
//
#include <hip/hip_runtime.h>
#include <math.h>

#define IN_DIM 512
#define DD 256

typedef _Float16 half8_t __attribute__((ext_vector_type(8)));
typedef __attribute__((ext_vector_type(4))) float f32x4_t;

// ---- prep: w2[i] = W[i,:] . a_w[D:2D]; one wave per row, coalesced ----
__global__ __launch_bounds__(256) void prep_w2(const float* __restrict__ W,
                                               const float* __restrict__ a_w,
                                               float* __restrict__ w2) {
  int row = (blockIdx.x * 256 + threadIdx.x) >> 6;  // 0..255
  int lane = threadIdx.x & 63;
  if (row >= DD) return;
  float4 wv = *reinterpret_cast<const float4*>(&W[(size_t)row * DD + lane * 4]);
  float4 av = *reinterpret_cast<const float4*>(&a_w[DD + lane * 4]);
  float s = wv.x * av.x + wv.y * av.y + wv.z * av.z + wv.w * av.w;
#pragma unroll
  for (int d = 32; d; d >>= 1) s += __shfl_xor(s, d, 64);
  if (lane == 0) w2[row] = s;
}

// ---- convert Wm_o to MFMA-fragment-ordered fp16 ----
__global__ void bconv_kernel(const float* __restrict__ Wm, _Float16* __restrict__ Bh) {
  int i = blockIdx.x * 256 + threadIdx.x;  // 0..131071
  int k = i >> 8, col = i & 255;
  int kc16 = k >> 5, kr = k & 31;
  int lane = ((kr >> 3) << 4) | (col & 15);
  int nf = col >> 4;
  int off = (((((kc16 << 4) + nf) << 6) + lane) << 3) + (kr & 7);
  Bh[off] = (_Float16)Wm[i];
}

__device__ __forceinline__ half8_t cvt8(const float4& a, const float4& b) {
  half8_t h;
  h[0] = (_Float16)a.x; h[1] = (_Float16)a.y; h[2] = (_Float16)a.z; h[3] = (_Float16)a.w;
  h[4] = (_Float16)b.x; h[5] = (_Float16)b.y; h[6] = (_Float16)b.z; h[7] = (_Float16)b.w;
  return h;
}

__device__ __forceinline__ void gload16(const void* g, void* l) {
  __builtin_amdgcn_global_load_lds(
      (const __attribute__((address_space(1))) void*)g,
      (__attribute__((address_space(3))) void*)l, 16, 0, 0);
}

// ---- MFMA GEMM (FROZEN from R16): 32 rows/wave, 128-row blocks, B via
// global_load_lds into triple-buffered LDS, counted vmcnt(8), full fences. ----
__global__ __launch_bounds__(256, 2) void map_gemm_mfma(
    const float* __restrict__ X, const _Float16* __restrict__ Bh,
    const float* __restrict__ bm, const float* __restrict__ w2,
    float* __restrict__ Yn, _Float16* __restrict__ Y16,
    float* __restrict__ wnorm, int M) {
  __shared__ _Float16 Bs[3][8192];  // 3 x 16KB
  const int t = threadIdx.x;
  const int wv = t >> 6;
  const int l = t & 63;
  const int c = l & 15;
  const int g = l >> 4;
  const int row0 = blockIdx.x * 128 + wv * 32;  // wave's 32-row strip

  int arow0 = row0 + c;       if (arow0 >= M) arow0 = M - 1;
  int arow1 = row0 + 16 + c;  if (arow1 >= M) arow1 = M - 1;
  const float* xrow0 = X + (size_t)arow0 * IN_DIM;
  const float* xrow1 = X + (size_t)arow1 * IN_DIM;

  f32x4_t acc[2][16];
#pragma unroll
  for (int rf = 0; rf < 2; ++rf)
#pragma unroll
    for (int n = 0; n < 16; ++n) acc[rf][n] = (f32x4_t){0.f, 0.f, 0.f, 0.f};

  const char* bbytes = reinterpret_cast<const char*>(Bh);
  const int lane16 = l * 16;

  float4 a0[2][2], a1[2][2];
#pragma unroll
  for (int j = 0; j < 4; ++j)
    gload16(bbytes + ((wv << 2) + j) * 1024 + lane16,
            (char*)&Bs[0][0] + ((wv << 2) + j) * 1024);
  a0[0][0] = *reinterpret_cast<const float4*>(xrow0 + g * 8);
  a0[0][1] = *reinterpret_cast<const float4*>(xrow0 + g * 8 + 4);
  a0[1][0] = *reinterpret_cast<const float4*>(xrow1 + g * 8);
  a0[1][1] = *reinterpret_cast<const float4*>(xrow1 + g * 8 + 4);
  asm volatile("" ::: "memory");  // pin batch0 before batch1 in vmcnt queue
#pragma unroll
  for (int j = 0; j < 4; ++j)
    gload16(bbytes + 16384 + ((wv << 2) + j) * 1024 + lane16,
            (char*)&Bs[1][0] + ((wv << 2) + j) * 1024);
  a1[0][0] = *reinterpret_cast<const float4*>(xrow0 + 32 + g * 8);
  a1[0][1] = *reinterpret_cast<const float4*>(xrow0 + 32 + g * 8 + 4);
  a1[1][0] = *reinterpret_cast<const float4*>(xrow1 + 32 + g * 8);
  a1[1][1] = *reinterpret_cast<const float4*>(xrow1 + 32 + g * 8 + 4);

#pragma unroll
  for (int kc = 0; kc < 16; ++kc) {
    if (kc < 15) {
      asm volatile("s_waitcnt vmcnt(8)" ::: "memory");
    } else {
      asm volatile("s_waitcnt vmcnt(0)" ::: "memory");
    }
    __builtin_amdgcn_s_barrier();
    asm volatile("" ::: "memory");
    __builtin_amdgcn_sched_barrier(0);

    half8_t ah0, ah1;
    if ((kc & 1) == 0) {
      ah0 = cvt8(a0[0][0], a0[0][1]);
      ah1 = cvt8(a0[1][0], a0[1][1]);
    } else {
      ah0 = cvt8(a1[0][0], a1[0][1]);
      ah1 = cvt8(a1[1][0], a1[1][1]);
    }

    if (kc < 14) {
      const char* gb = bbytes + (kc + 2) * 16384;
      char* lb = (char*)&Bs[(kc + 2) % 3][0];
#pragma unroll
      for (int j = 0; j < 4; ++j)
        gload16(gb + ((wv << 2) + j) * 1024 + lane16, lb + ((wv << 2) + j) * 1024);
      const float* xp0 = xrow0 + (kc + 2) * 32 + g * 8;
      const float* xp1 = xrow1 + (kc + 2) * 32 + g * 8;
      if ((kc & 1) == 0) {
        a0[0][0] = *reinterpret_cast<const float4*>(xp0);
        a0[0][1] = *reinterpret_cast<const float4*>(xp0 + 4);
        a0[1][0] = *reinterpret_cast<const float4*>(xp1);
        a0[1][1] = *reinterpret_cast<const float4*>(xp1 + 4);
      } else {
        a1[0][0] = *reinterpret_cast<const float4*>(xp0);
        a1[0][1] = *reinterpret_cast<const float4*>(xp0 + 4);
        a1[1][0] = *reinterpret_cast<const float4*>(xp1);
        a1[1][1] = *reinterpret_cast<const float4*>(xp1 + 4);
      }
    }

    const _Float16* bp = &Bs[kc % 3][0];
    __builtin_amdgcn_s_setprio(1);
#pragma unroll
    for (int n = 0; n < 16; ++n) {
      half8_t bh = *reinterpret_cast<const half8_t*>(&bp[n * 512 + l * 8]);
      acc[0][n] = __builtin_amdgcn_mfma_f32_16x16x32_f16(ah0, bh, acc[0][n], 0, 0, 0);
      acc[1][n] = __builtin_amdgcn_mfma_f32_16x16x32_f16(ah1, bh, acc[1][n], 0, 0, 0);
    }
    __builtin_amdgcn_s_setprio(0);
  }

#pragma unroll
  for (int rf = 0; rf < 2; ++rf) {
    float ssq[4] = {0.f, 0.f, 0.f, 0.f}, dtq[4] = {0.f, 0.f, 0.f, 0.f};
#pragma unroll
    for (int n = 0; n < 16; ++n) {
      float bvn = bm[n * 16 + c];
      float wvn = w2[n * 16 + c];
#pragma unroll
      for (int q = 0; q < 4; ++q) {
        float v = acc[rf][n][q] + bvn;
        v = v > 0.f ? v : 0.f;
        acc[rf][n][q] = v;
        ssq[q] = fmaf(v, v, ssq[q]);
        dtq[q] = fmaf(v, wvn, dtq[q]);
      }
    }
#pragma unroll
    for (int q = 0; q < 4; ++q) {
#pragma unroll
      for (int d = 1; d < 16; d <<= 1) {
        ssq[q] += __shfl_xor(ssq[q], d, 16);
        dtq[q] += __shfl_xor(dtq[q], d, 16);
      }
    }
    float inv[4];
#pragma unroll
    for (int q = 0; q < 4; ++q) {
      float nr = sqrtf(ssq[q]);
      inv[q] = 1.f / fmaxf(nr, 1e-12f);
      int r = row0 + rf * 16 + g * 4 + q;
      if (c == 0 && r < M) wnorm[r] = expf(dtq[q]) * nr;
    }
#pragma unroll
    for (int q = 0; q < 4; ++q) {
      int r = row0 + rf * 16 + g * 4 + q;
      if (r < M) {
#pragma unroll
        for (int n = 0; n < 16; ++n) {
          float v = acc[rf][n][q] * inv[q];
          Yn[(size_t)r * DD + n * 16 + c] = v;
          Y16[(size_t)r * DD + n * 16 + c] = (_Float16)v;
        }
      }
    }
  }
}

// ---- CSR build ----
__global__ void hist_kernel(const int* __restrict__ src, int* __restrict__ deg, int E) {
  int i = blockIdx.x * blockDim.x + threadIdx.x;
  if (i < E) atomicAdd(&deg[src[i]], 1);
}

// per-block sums (raw, no exclusive pass needed anymore)
__global__ __launch_bounds__(256) void scan_part(const int* __restrict__ deg,
                                                 int* __restrict__ bsum, int NP) {
  __shared__ int s[256];
  int t = threadIdx.x, b = blockIdx.x;
  int i0 = (b * 256 + t) * 2;
  int v0 = (i0 < NP) ? deg[i0] : 0;
  int v1 = (i0 + 1 < NP) ? deg[i0 + 1] : 0;
  s[t] = v0 + v1;
  __syncthreads();
  for (int off = 128; off; off >>= 1) {
    if (t < off) s[t] += s[t + off];
    __syncthreads();
  }
  if (t == 0) bsum[b] = s[0];
}

// fused: recompute own block base from raw bsum (256 adds), local scan, emit
__global__ __launch_bounds__(256) void scan_fin2(const int* __restrict__ deg,
                                                 const int* __restrict__ bsum,
                                                 int* __restrict__ rowptr,
                                                 int* __restrict__ cursor, int NP) {
  __shared__ int s[256];
  __shared__ int base_s;
  int t = threadIdx.x, b = blockIdx.x;
  int v = (t < b) ? bsum[t] : 0;
  s[t] = v;
  __syncthreads();
  for (int off = 128; off; off >>= 1) {
    if (t < off) s[t] += s[t + off];
    __syncthreads();
  }
  if (t == 0) base_s = s[0];
  __syncthreads();
  int base0 = base_s;
  __syncthreads();  // s[] about to be reused
  int i0 = (b * 256 + t) * 2;
  int v0 = (i0 < NP) ? deg[i0] : 0;
  int v1 = (i0 + 1 < NP) ? deg[i0 + 1] : 0;
  int local = v0 + v1;
  s[t] = local;
  __syncthreads();
  for (int off = 1; off < 256; off <<= 1) {
    int u = (t >= off) ? s[t - off] : 0;
    __syncthreads();
    s[t] += u;
    __syncthreads();
  }
  int myb = base0 + s[t] - local;
  if (i0 < NP) { rowptr[i0] = myb; cursor[i0] = myb; }
  if (i0 + 1 < NP) { rowptr[i0 + 1] = myb + v0; cursor[i0 + 1] = myb + v0; }
  if (b == gridDim.x - 1 && t == 255) rowptr[NP] = base0 + s[255];
}

__global__ void fill_kernel(const int* __restrict__ src, const int* __restrict__ dst,
                            int* __restrict__ cursor, int* __restrict__ ebuf, int E) {
  int i = blockIdx.x * blockDim.x + threadIdx.x;
  if (i < E) {
    int pos = atomicAdd(&cursor[src[i]], 1);
    ebuf[pos] = dst[i];
  }
}

// ---- per-segment: out = l2norm(sum wnorm[d] * hon16[d])
// 16 lanes per node (4 independent node chains per wave -> 4x MLP).
// Each lane owns 16 of the 256 cols (32B of the fp16 row).
// GRID: 16 nodes per block -> (NP+15)/16 blocks (R17 bug: was /4/256). ----
__global__ __launch_bounds__(256) void agg_kernel(const int* __restrict__ rowptr,
                                                  const int* __restrict__ ebuf,
                                                  const float* __restrict__ wnorm,
                                                  const _Float16* __restrict__ hon16,
                                                  float* __restrict__ agg, int NP) {
  long gid = (long)blockIdx.x * blockDim.x + threadIdx.x;
  int wid = (int)(gid >> 6);
  int lane = threadIdx.x & 63;
  int sg = lane >> 4;      // node slot within wave
  int li = lane & 15;      // lane within node group
  int p = wid * 4 + sg;
  if (p >= NP) return;
  int beg = rowptr[p], end = rowptr[p + 1];
  float acc[16];
#pragma unroll
  for (int k = 0; k < 16; ++k) acc[k] = 0.f;
  if (beg < end) {
    // 1-ahead pipelined gather: 2 x half8 (32B) per lane per row
    int d = ebuf[beg];
    float w = wnorm[d];
    const half8_t* rp = reinterpret_cast<const half8_t*>(&hon16[(size_t)d * DD + li * 16]);
    half8_t v0 = rp[0], v1 = rp[1];
    for (int j = beg + 1; j <= end; ++j) {
      half8_t n0, n1;
      float wn_ = 0.f;
      bool have = (j < end);
      if (have) {
        int dn = ebuf[j];
        wn_ = wnorm[dn];
        const half8_t* np_ = reinterpret_cast<const half8_t*>(&hon16[(size_t)dn * DD + li * 16]);
        n0 = np_[0]; n1 = np_[1];
      }
#pragma unroll
      for (int k = 0; k < 8; ++k) {
        acc[k] = fmaf(w, (float)v0[k], acc[k]);
        acc[8 + k] = fmaf(w, (float)v1[k], acc[8 + k]);
      }
      if (have) { w = wn_; v0 = n0; v1 = n1; }
    }
  }
  float ss = 0.f;
#pragma unroll
  for (int k = 0; k < 16; ++k) ss = fmaf(acc[k], acc[k], ss);
#pragma unroll
  for (int d2 = 8; d2 > 0; d2 >>= 1) ss += __shfl_xor(ss, d2, 16);
  float inv = 1.0f / fmaxf(sqrtf(ss), 1e-12f);
  float* op = &agg[(size_t)p * DD + li * 16];
#pragma unroll
  for (int k = 0; k < 4; ++k) {
    float4 o = {acc[k * 4] * inv, acc[k * 4 + 1] * inv,
                acc[k * 4 + 2] * inv, acc[k * 4 + 3] * inv};
    *reinterpret_cast<float4*>(op + k * 4) = o;
  }
}

extern "C" void kernel_launch(void* const* d_in, const int* in_sizes, int n_in,
                              void* d_out, int out_size, void* d_ws, size_t ws_size,
                              hipStream_t stream) {
  const float* feat_other = (const float*)d_in[1];
  const int* src = (const int*)d_in[2];
  const int* dst = (const int*)d_in[3];
  const float* Wm_o = (const float*)d_in[6];
  const float* bm_o = (const float*)d_in[7];
  const float* W = (const float*)d_in[8];
  const float* a_w = (const float*)d_in[10];

  const int NP = in_sizes[0] / IN_DIM;
  const int NO = in_sizes[1] / IN_DIM;
  const int E = in_sizes[2];

  float* out = (float*)d_out;
  float* agg_out = out;                      // [NP, DD] (normalized agg)
  float* ho_out = out + (size_t)NP * DD;     // [NO, DD] (normalized ho)

  // workspace layout (floats)
  float* ws = (float*)d_ws;
  float* wnorm = ws;                          // NO
  float* w2 = wnorm + NO;                     // 256
  int* deg = (int*)(w2 + 256);                // NP (memset 0)
  int* rowptr = deg + NP;                     // NP+1
  int* cursor = rowptr + NP + 1;              // NP
  int* bsum = cursor + NP;                    // 256
  int* ebuf = bsum + 256;                     // E
  size_t foff = (size_t)NO + 256 + NP + (NP + 1) + NP + 256 + E;
  foff = (foff + 3) & ~(size_t)3;             // 16B align
  _Float16* Bh = (_Float16*)(ws + foff);      // 131072 halves
  _Float16* Y16 = Bh + (size_t)IN_DIM * DD;   // NO * DD halves

  hipMemsetAsync(deg, 0, (size_t)NP * sizeof(int), stream);

  prep_w2<<<64, 256, 0, stream>>>(W, a_w, w2);
  bconv_kernel<<<(IN_DIM * DD) / 256, 256, 0, stream>>>(Wm_o, Bh);

  map_gemm_mfma<<<(NO + 127) / 128, 256, 0, stream>>>(
      feat_other, Bh, bm_o, w2, ho_out, Y16, wnorm, NO);

  hist_kernel<<<(E + 255) / 256, 256, 0, stream>>>(src, deg, E);
  scan_part<<<256, 256, 0, stream>>>(deg, bsum, NP);
  scan_fin2<<<256, 256, 0, stream>>>(deg, bsum, rowptr, cursor, NP);
  fill_kernel<<<(E + 255) / 256, 256, 0, stream>>>(src, dst, cursor, ebuf, E);

  agg_kernel<<<(NP + 15) / 16, 256, 0, stream>>>(
      rowptr, ebuf, wnorm, Y16, agg_out, NP);
}

// Round 19
// 331.937 us; speedup vs baseline: 1.3805x; 1.0005x over previous
//
#include <hip/hip_runtime.h>
#include <math.h>

#define IN_DIM 512
#define DD 256

typedef _Float16 half8_t __attribute__((ext_vector_type(8)));
typedef __attribute__((ext_vector_type(4))) float f32x4_t;

// ---- prep: w2[i] = W[i,:] . a_w[D:2D]; one wave per row, coalesced ----
__global__ __launch_bounds__(256) void prep_w2(const float* __restrict__ W,
                                               const float* __restrict__ a_w,
                                               float* __restrict__ w2) {
  int row = (blockIdx.x * 256 + threadIdx.x) >> 6;  // 0..255
  int lane = threadIdx.x & 63;
  if (row >= DD) return;
  float4 wv = *reinterpret_cast<const float4*>(&W[(size_t)row * DD + lane * 4]);
  float4 av = *reinterpret_cast<const float4*>(&a_w[DD + lane * 4]);
  float s = wv.x * av.x + wv.y * av.y + wv.z * av.z + wv.w * av.w;
#pragma unroll
  for (int d = 32; d; d >>= 1) s += __shfl_xor(s, d, 64);
  if (lane == 0) w2[row] = s;
}

// ---- convert Wm_o to MFMA-fragment-ordered fp16 ----
__global__ void bconv_kernel(const float* __restrict__ Wm, _Float16* __restrict__ Bh) {
  int i = blockIdx.x * 256 + threadIdx.x;  // 0..131071
  int k = i >> 8, col = i & 255;
  int kc16 = k >> 5, kr = k & 31;
  int lane = ((kr >> 3) << 4) | (col & 15);
  int nf = col >> 4;
  int off = (((((kc16 << 4) + nf) << 6) + lane) << 3) + (kr & 7);
  Bh[off] = (_Float16)Wm[i];
}

__device__ __forceinline__ half8_t cvt8(const float4& a, const float4& b) {
  half8_t h;
  h[0] = (_Float16)a.x; h[1] = (_Float16)a.y; h[2] = (_Float16)a.z; h[3] = (_Float16)a.w;
  h[4] = (_Float16)b.x; h[5] = (_Float16)b.y; h[6] = (_Float16)b.z; h[7] = (_Float16)b.w;
  return h;
}

__device__ __forceinline__ void gload16(const void* g, void* l) {
  __builtin_amdgcn_global_load_lds(
      (const __attribute__((address_space(1))) void*)g,
      (__attribute__((address_space(3))) void*)l, 16, 0, 0);
}

// ---- MFMA GEMM: 32 rows/wave, 128-row blocks; B via global_load_lds into
// QUAD-buffered LDS with 3-step-ahead prefetch (counted vmcnt(16) steady
// state -> ~1800cyc of HBM-latency cover vs ~1000 at 2-deep). A 3-deep
// register sets. All R14 fences kept. ----
__global__ __launch_bounds__(256, 2) void map_gemm_mfma(
    const float* __restrict__ X, const _Float16* __restrict__ Bh,
    const float* __restrict__ bm, const float* __restrict__ w2,
    float* __restrict__ Yn, _Float16* __restrict__ Y16,
    float* __restrict__ wnorm, int M) {
  __shared__ _Float16 Bs[4][8192];  // 4 x 16KB
  const int t = threadIdx.x;
  const int wv = t >> 6;
  const int l = t & 63;
  const int c = l & 15;
  const int g = l >> 4;
  const int row0 = blockIdx.x * 128 + wv * 32;  // wave's 32-row strip

  int arow0 = row0 + c;       if (arow0 >= M) arow0 = M - 1;
  int arow1 = row0 + 16 + c;  if (arow1 >= M) arow1 = M - 1;
  const float* xrow0 = X + (size_t)arow0 * IN_DIM;
  const float* xrow1 = X + (size_t)arow1 * IN_DIM;

  f32x4_t acc[2][16];
#pragma unroll
  for (int rf = 0; rf < 2; ++rf)
#pragma unroll
    for (int n = 0; n < 16; ++n) acc[rf][n] = (f32x4_t){0.f, 0.f, 0.f, 0.f};

  const char* bbytes = reinterpret_cast<const char*>(Bh);
  const int lane16 = l * 16;

  // 3-deep A register sets (named; indices static under full unroll)
  float4 A0[2][2], A1[2][2], A2[2][2];

  // ---- prologue: batches 0,1,2 (each: 4 gload_lds + 4 float4), fence-pinned ----
#pragma unroll
  for (int j = 0; j < 4; ++j)
    gload16(bbytes + ((wv << 2) + j) * 1024 + lane16,
            (char*)&Bs[0][0] + ((wv << 2) + j) * 1024);
  A0[0][0] = *reinterpret_cast<const float4*>(xrow0 + g * 8);
  A0[0][1] = *reinterpret_cast<const float4*>(xrow0 + g * 8 + 4);
  A0[1][0] = *reinterpret_cast<const float4*>(xrow1 + g * 8);
  A0[1][1] = *reinterpret_cast<const float4*>(xrow1 + g * 8 + 4);
  asm volatile("" ::: "memory");
#pragma unroll
  for (int j = 0; j < 4; ++j)
    gload16(bbytes + 16384 + ((wv << 2) + j) * 1024 + lane16,
            (char*)&Bs[1][0] + ((wv << 2) + j) * 1024);
  A1[0][0] = *reinterpret_cast<const float4*>(xrow0 + 32 + g * 8);
  A1[0][1] = *reinterpret_cast<const float4*>(xrow0 + 32 + g * 8 + 4);
  A1[1][0] = *reinterpret_cast<const float4*>(xrow1 + 32 + g * 8);
  A1[1][1] = *reinterpret_cast<const float4*>(xrow1 + 32 + g * 8 + 4);
  asm volatile("" ::: "memory");
#pragma unroll
  for (int j = 0; j < 4; ++j)
    gload16(bbytes + 32768 + ((wv << 2) + j) * 1024 + lane16,
            (char*)&Bs[2][0] + ((wv << 2) + j) * 1024);
  A2[0][0] = *reinterpret_cast<const float4*>(xrow0 + 64 + g * 8);
  A2[0][1] = *reinterpret_cast<const float4*>(xrow0 + 64 + g * 8 + 4);
  A2[1][0] = *reinterpret_cast<const float4*>(xrow1 + 64 + g * 8);
  A2[1][1] = *reinterpret_cast<const float4*>(xrow1 + 64 + g * 8 + 4);

#pragma unroll
  for (int kc = 0; kc < 16; ++kc) {
    // retire own-wave batch kc: outstanding = {kc,kc+1,kc+2} = 24 ops -> 16
    if (kc <= 13) {
      asm volatile("s_waitcnt vmcnt(16)" ::: "memory");
    } else if (kc == 14) {
      asm volatile("s_waitcnt vmcnt(8)" ::: "memory");
    } else {
      asm volatile("s_waitcnt vmcnt(0)" ::: "memory");
    }
    __builtin_amdgcn_s_barrier();
    asm volatile("" ::: "memory");           // IR fence
    __builtin_amdgcn_sched_barrier(0);       // MIR fence

    // A fragments of batch kc (set kc%3) -- read BEFORE overwrite below
    half8_t ah0, ah1;
    if (kc % 3 == 0)      { ah0 = cvt8(A0[0][0], A0[0][1]); ah1 = cvt8(A0[1][0], A0[1][1]); }
    else if (kc % 3 == 1) { ah0 = cvt8(A1[0][0], A1[0][1]); ah1 = cvt8(A1[1][0], A1[1][1]); }
    else                  { ah0 = cvt8(A2[0][0], A2[0][1]); ah1 = cvt8(A2[1][0], A2[1][1]); }

    // issue batch kc+3 -> Bs[(kc+3)%4] (readers closed at this barrier), A set kc%3
    if (kc <= 12) {
      const char* gb = bbytes + (kc + 3) * 16384;
      char* lb = (char*)&Bs[(kc + 3) % 4][0];
#pragma unroll
      for (int j = 0; j < 4; ++j)
        gload16(gb + ((wv << 2) + j) * 1024 + lane16, lb + ((wv << 2) + j) * 1024);
      const float* xp0 = xrow0 + (kc + 3) * 32 + g * 8;
      const float* xp1 = xrow1 + (kc + 3) * 32 + g * 8;
      if (kc % 3 == 0) {
        A0[0][0] = *reinterpret_cast<const float4*>(xp0);
        A0[0][1] = *reinterpret_cast<const float4*>(xp0 + 4);
        A0[1][0] = *reinterpret_cast<const float4*>(xp1);
        A0[1][1] = *reinterpret_cast<const float4*>(xp1 + 4);
      } else if (kc % 3 == 1) {
        A1[0][0] = *reinterpret_cast<const float4*>(xp0);
        A1[0][1] = *reinterpret_cast<const float4*>(xp0 + 4);
        A1[1][0] = *reinterpret_cast<const float4*>(xp1);
        A1[1][1] = *reinterpret_cast<const float4*>(xp1 + 4);
      } else {
        A2[0][0] = *reinterpret_cast<const float4*>(xp0);
        A2[0][1] = *reinterpret_cast<const float4*>(xp0 + 4);
        A2[1][0] = *reinterpret_cast<const float4*>(xp1);
        A2[1][1] = *reinterpret_cast<const float4*>(xp1 + 4);
      }
    }

    const _Float16* bp = &Bs[kc % 4][0];
    __builtin_amdgcn_s_setprio(1);
#pragma unroll
    for (int n = 0; n < 16; ++n) {
      half8_t bh = *reinterpret_cast<const half8_t*>(&bp[n * 512 + l * 8]);
      acc[0][n] = __builtin_amdgcn_mfma_f32_16x16x32_f16(ah0, bh, acc[0][n], 0, 0, 0);
      acc[1][n] = __builtin_amdgcn_mfma_f32_16x16x32_f16(ah1, bh, acc[1][n], 0, 0, 0);
    }
    __builtin_amdgcn_s_setprio(0);
  }

#pragma unroll
  for (int rf = 0; rf < 2; ++rf) {
    float ssq[4] = {0.f, 0.f, 0.f, 0.f}, dtq[4] = {0.f, 0.f, 0.f, 0.f};
#pragma unroll
    for (int n = 0; n < 16; ++n) {
      float bvn = bm[n * 16 + c];
      float wvn = w2[n * 16 + c];
#pragma unroll
      for (int q = 0; q < 4; ++q) {
        float v = acc[rf][n][q] + bvn;
        v = v > 0.f ? v : 0.f;
        acc[rf][n][q] = v;
        ssq[q] = fmaf(v, v, ssq[q]);
        dtq[q] = fmaf(v, wvn, dtq[q]);
      }
    }
#pragma unroll
    for (int q = 0; q < 4; ++q) {
#pragma unroll
      for (int d = 1; d < 16; d <<= 1) {
        ssq[q] += __shfl_xor(ssq[q], d, 16);
        dtq[q] += __shfl_xor(dtq[q], d, 16);
      }
    }
    float inv[4];
#pragma unroll
    for (int q = 0; q < 4; ++q) {
      float nr = sqrtf(ssq[q]);
      inv[q] = 1.f / fmaxf(nr, 1e-12f);
      int r = row0 + rf * 16 + g * 4 + q;
      if (c == 0 && r < M) wnorm[r] = expf(dtq[q]) * nr;
    }
#pragma unroll
    for (int q = 0; q < 4; ++q) {
      int r = row0 + rf * 16 + g * 4 + q;
      if (r < M) {
#pragma unroll
        for (int n = 0; n < 16; ++n) {
          float v = acc[rf][n][q] * inv[q];
          Yn[(size_t)r * DD + n * 16 + c] = v;
          Y16[(size_t)r * DD + n * 16 + c] = (_Float16)v;
        }
      }
    }
  }
}

// ---- CSR build ----
__global__ void hist_kernel(const int* __restrict__ src, int* __restrict__ deg, int E) {
  int i = blockIdx.x * blockDim.x + threadIdx.x;
  if (i < E) atomicAdd(&deg[src[i]], 1);
}

__global__ __launch_bounds__(256) void scan_part(const int* __restrict__ deg,
                                                 int* __restrict__ bsum, int NP) {
  __shared__ int s[256];
  int t = threadIdx.x, b = blockIdx.x;
  int i0 = (b * 256 + t) * 2;
  int v0 = (i0 < NP) ? deg[i0] : 0;
  int v1 = (i0 + 1 < NP) ? deg[i0 + 1] : 0;
  s[t] = v0 + v1;
  __syncthreads();
  for (int off = 128; off; off >>= 1) {
    if (t < off) s[t] += s[t + off];
    __syncthreads();
  }
  if (t == 0) bsum[b] = s[0];
}

__global__ __launch_bounds__(256) void scan_fin2(const int* __restrict__ deg,
                                                 const int* __restrict__ bsum,
                                                 int* __restrict__ rowptr,
                                                 int* __restrict__ cursor, int NP) {
  __shared__ int s[256];
  __shared__ int base_s;
  int t = threadIdx.x, b = blockIdx.x;
  int v = (t < b) ? bsum[t] : 0;
  s[t] = v;
  __syncthreads();
  for (int off = 128; off; off >>= 1) {
    if (t < off) s[t] += s[t + off];
    __syncthreads();
  }
  if (t == 0) base_s = s[0];
  __syncthreads();
  int base0 = base_s;
  __syncthreads();
  int i0 = (b * 256 + t) * 2;
  int v0 = (i0 < NP) ? deg[i0] : 0;
  int v1 = (i0 + 1 < NP) ? deg[i0 + 1] : 0;
  int local = v0 + v1;
  s[t] = local;
  __syncthreads();
  for (int off = 1; off < 256; off <<= 1) {
    int u = (t >= off) ? s[t - off] : 0;
    __syncthreads();
    s[t] += u;
    __syncthreads();
  }
  int myb = base0 + s[t] - local;
  if (i0 < NP) { rowptr[i0] = myb; cursor[i0] = myb; }
  if (i0 + 1 < NP) { rowptr[i0 + 1] = myb + v0; cursor[i0 + 1] = myb + v0; }
  if (b == gridDim.x - 1 && t == 255) rowptr[NP] = base0 + s[255];
}

__global__ void fill_kernel(const int* __restrict__ src, const int* __restrict__ dst,
                            int* __restrict__ cursor, int* __restrict__ ebuf, int E) {
  int i = blockIdx.x * blockDim.x + threadIdx.x;
  if (i < E) {
    int pos = atomicAdd(&cursor[src[i]], 1);
    ebuf[pos] = dst[i];
  }
}

// ---- per-segment: out = l2norm(sum wnorm[d] * hon16[d]); 16 lanes/node ----
__global__ __launch_bounds__(256) void agg_kernel(const int* __restrict__ rowptr,
                                                  const int* __restrict__ ebuf,
                                                  const float* __restrict__ wnorm,
                                                  const _Float16* __restrict__ hon16,
                                                  float* __restrict__ agg, int NP) {
  long gid = (long)blockIdx.x * blockDim.x + threadIdx.x;
  int wid = (int)(gid >> 6);
  int lane = threadIdx.x & 63;
  int sg = lane >> 4;
  int li = lane & 15;
  int p = wid * 4 + sg;
  if (p >= NP) return;
  int beg = rowptr[p], end = rowptr[p + 1];
  float acc[16];
#pragma unroll
  for (int k = 0; k < 16; ++k) acc[k] = 0.f;
  if (beg < end) {
    int d = ebuf[beg];
    float w = wnorm[d];
    const half8_t* rp = reinterpret_cast<const half8_t*>(&hon16[(size_t)d * DD + li * 16]);
    half8_t v0 = rp[0], v1 = rp[1];
    for (int j = beg + 1; j <= end; ++j) {
      half8_t n0, n1;
      float wn_ = 0.f;
      bool have = (j < end);
      if (have) {
        int dn = ebuf[j];
        wn_ = wnorm[dn];
        const half8_t* np_ = reinterpret_cast<const half8_t*>(&hon16[(size_t)dn * DD + li * 16]);
        n0 = np_[0]; n1 = np_[1];
      }
#pragma unroll
      for (int k = 0; k < 8; ++k) {
        acc[k] = fmaf(w, (float)v0[k], acc[k]);
        acc[8 + k] = fmaf(w, (float)v1[k], acc[8 + k]);
      }
      if (have) { w = wn_; v0 = n0; v1 = n1; }
    }
  }
  float ss = 0.f;
#pragma unroll
  for (int k = 0; k < 16; ++k) ss = fmaf(acc[k], acc[k], ss);
#pragma unroll
  for (int d2 = 8; d2 > 0; d2 >>= 1) ss += __shfl_xor(ss, d2, 16);
  float inv = 1.0f / fmaxf(sqrtf(ss), 1e-12f);
  float* op = &agg[(size_t)p * DD + li * 16];
#pragma unroll
  for (int k = 0; k < 4; ++k) {
    float4 o = {acc[k * 4] * inv, acc[k * 4 + 1] * inv,
                acc[k * 4 + 2] * inv, acc[k * 4 + 3] * inv};
    *reinterpret_cast<float4*>(op + k * 4) = o;
  }
}

extern "C" void kernel_launch(void* const* d_in, const int* in_sizes, int n_in,
                              void* d_out, int out_size, void* d_ws, size_t ws_size,
                              hipStream_t stream) {
  const float* feat_other = (const float*)d_in[1];
  const int* src = (const int*)d_in[2];
  const int* dst = (const int*)d_in[3];
  const float* Wm_o = (const float*)d_in[6];
  const float* bm_o = (const float*)d_in[7];
  const float* W = (const float*)d_in[8];
  const float* a_w = (const float*)d_in[10];

  const int NP = in_sizes[0] / IN_DIM;
  const int NO = in_sizes[1] / IN_DIM;
  const int E = in_sizes[2];

  float* out = (float*)d_out;
  float* agg_out = out;                      // [NP, DD]
  float* ho_out = out + (size_t)NP * DD;     // [NO, DD]

  float* ws = (float*)d_ws;
  float* wnorm = ws;                          // NO
  float* w2 = wnorm + NO;                     // 256
  int* deg = (int*)(w2 + 256);                // NP (memset 0)
  int* rowptr = deg + NP;                     // NP+1
  int* cursor = rowptr + NP + 1;              // NP
  int* bsum = cursor + NP;                    // 256
  int* ebuf = bsum + 256;                     // E
  size_t foff = (size_t)NO + 256 + NP + (NP + 1) + NP + 256 + E;
  foff = (foff + 3) & ~(size_t)3;             // 16B align
  _Float16* Bh = (_Float16*)(ws + foff);      // 131072 halves
  _Float16* Y16 = Bh + (size_t)IN_DIM * DD;   // NO * DD halves

  hipMemsetAsync(deg, 0, (size_t)NP * sizeof(int), stream);

  prep_w2<<<64, 256, 0, stream>>>(W, a_w, w2);
  bconv_kernel<<<(IN_DIM * DD) / 256, 256, 0, stream>>>(Wm_o, Bh);

  map_gemm_mfma<<<(NO + 127) / 128, 256, 0, stream>>>(
      feat_other, Bh, bm_o, w2, ho_out, Y16, wnorm, NO);

  hist_kernel<<<(E + 255) / 256, 256, 0, stream>>>(src, deg, E);
  scan_part<<<256, 256, 0, stream>>>(deg, bsum, NP);
  scan_fin2<<<256, 256, 0, stream>>>(deg, bsum, rowptr, cursor, NP);
  fill_kernel<<<(E + 255) / 256, 256, 0, stream>>>(src, dst, cursor, ebuf, E);

  agg_kernel<<<(NP + 15) / 16, 256, 0, stream>>>(
      rowptr, ebuf, wnorm, Y16, agg_out, NP);
}